// Round 17
// baseline (2088.689 us; speedup 1.0000x reference)
//
#include <hip/hip_runtime.h>
#include <cstdint>
#include <cmath>

typedef __attribute__((ext_vector_type(8))) short short8;   // 8 bf16 (4 VGPRs)
typedef __attribute__((ext_vector_type(4))) float floatx4;  // MFMA C/D

// round-to-nearest-even fp32->bf16, packed pair -> uint (lo = x, hi = y)
__device__ __forceinline__ unsigned pk_bf16(float x, float y) {
    unsigned ux = __float_as_uint(x); ux = ux + 0x7fffu + ((ux >> 16) & 1u);
    unsigned uy = __float_as_uint(y); uy = uy + 0x7fffu + ((uy >> 16) & 1u);
    return (ux >> 16) | (uy & 0xffff0000u);
}
__device__ __forceinline__ unsigned short bf16r(float x) {
    unsigned ux = __float_as_uint(x);
    return (unsigned short)((ux + 0x7fffu + ((ux >> 16) & 1u)) >> 16);
}
__device__ __forceinline__ float bf16d(unsigned short v) {
    return __uint_as_float((unsigned)v << 16);
}

// ---------------------------------------------------------------------------
// Kernel 1: fused embedding gather + input projections via bf16 MFMA.
// (unchanged — validated; X output bf16)
// ---------------------------------------------------------------------------
__global__ __launch_bounds__(256) void proj_kernel(
    const int* __restrict__ word_ids, const float* __restrict__ embed,
    const float* __restrict__ w_ih_f, const float* __restrict__ b_f,
    const float* __restrict__ w_ih_b, const float* __restrict__ b_b,
    unsigned short* __restrict__ XF, unsigned short* __restrict__ XB,
    int t0, int lgL)
{
    __shared__ unsigned short As[64][264];   // 64 x 256 bf16, +8 pad
    __shared__ unsigned short Bs[64][264];
    __shared__ int idx[64];

    const int tid = threadIdx.x;
    const int jt  = blockIdx.x;   // 0..15  (j tile)
    const int nt  = blockIdx.y;   // 0..L-1 (n tile; n = b*L + tl)
    const int dir = blockIdx.z;   // 0..1
    const int Lm1 = (1 << lgL) - 1;
    const float* __restrict__ W    = dir ? w_ih_b : w_ih_f;
    const float* __restrict__ bias = dir ? b_b : b_f;
    unsigned short* __restrict__ Xout = dir ? XB : XF;

    if (tid < 64) {
        int n  = nt * 64 + tid;
        int b  = n >> lgL;
        int tl = n & Lm1;
        int tg = dir ? (511 - (t0 + tl)) : (t0 + tl);
        idx[tid] = word_ids[b * 512 + tg];
    }
    __syncthreads();

    #pragma unroll
    for (int i = 0; i < 16; ++i) {
        int flat = i * 256 + tid;        // 0..4095 float4 units
        int r  = flat >> 6;              // row 0..63
        int kq = flat & 63;              // k = kq*4
        floatx4 a = *(const floatx4*)&embed[(size_t)idx[r] * 256 + kq * 4];
        *(uint2*)&As[r][kq * 4] = make_uint2(pk_bf16(a.x, a.y), pk_bf16(a.z, a.w));
        floatx4 wv = *(const floatx4*)&W[(size_t)(jt * 64 + r) * 256 + kq * 4];
        *(uint2*)&Bs[r][kq * 4] = make_uint2(pk_bf16(wv.x, wv.y), pk_bf16(wv.z, wv.w));
    }
    __syncthreads();

    const int w    = tid >> 6;     // wave 0..3: n-rows [w*16, w*16+16)
    const int lane = tid & 63;
    const int q    = lane >> 4;    // k-quad
    const int lr   = lane & 15;

    short8 af[8];
    #pragma unroll
    for (int ks = 0; ks < 8; ++ks)
        af[ks] = *(const short8*)&As[w * 16 + lr][ks * 32 + q * 8];

    floatx4 acc[4];
    #pragma unroll
    for (int jt4 = 0; jt4 < 4; ++jt4) {
        floatx4 c = {0.f, 0.f, 0.f, 0.f};
        #pragma unroll
        for (int ks = 0; ks < 8; ++ks) {
            short8 bf = *(const short8*)&Bs[jt4 * 16 + lr][ks * 32 + q * 8];
            c = __builtin_amdgcn_mfma_f32_16x16x32_bf16(af[ks], bf, c, 0, 0, 0);
        }
        acc[jt4] = c;
    }

    #pragma unroll
    for (int jt4 = 0; jt4 < 4; ++jt4) {
        int j = jt * 64 + jt4 * 16 + lr;
        float bj = bias[j];
        #pragma unroll
        for (int reg = 0; reg < 4; ++reg) {
            int n  = nt * 64 + w * 16 + q * 4 + reg;
            int b  = n >> lgL;
            int tl = n & Lm1;
            Xout[((size_t)tl * 64 + b) * 1024 + j] = bf16r(acc[jt4][reg] + bj);
        }
    }
}

// ---------------------------------------------------------------------------
// Kernel 2: BiLSTM scan — restructured to FIT the 128-arch-VGPR cap.
// Finding (r9-r16): the backend caps MFMA kernels at 128 arch VGPRs per
// wave regardless of launch_bounds / waves_per_eu / amdgpu_num_vgpr; any
// weight residency beyond that spills to scratch (~256 KB/block/step L2
// reload = the measured ~4900 cyc/step).
// Fix: 1024 threads / 16 waves. Wave w owns 64 rows (gate = w>>2, unit
// quarter = w&3) = 4 N-tiles: 3 in registers (96 VGPR) + 1 in LDS
// (16 waves x 8 KB = 128 KB). ALL weights resident, zero L2 streaming.
// ks-outer phase A: 1 live A-frag + 4 live accumulators; demand ~134 of
// 128 (minor spill at most). 4 waves/SIMD doubles latency hiding vs r11.
// Same validated 2-barrier step protocol, M=2 batches/block, 64 blocks.
// ---------------------------------------------------------------------------
__global__ __launch_bounds__(1024, 1) void lstm_scan(
    const unsigned short* __restrict__ XF, const unsigned short* __restrict__ XB,
    const float* __restrict__ w_hh_f, const float* __restrict__ w_hh_b,
    float* __restrict__ hf, float* __restrict__ hb,
    float* __restrict__ state_c, float* __restrict__ state_h, int t0, int t1)
{
    __shared__ unsigned short Ah[2][264];      // h(t-1) bf16: [batch][k=256(+8)]
    __shared__ float scr[4][2][256];           // gate preacts: [gate][batch][unit]
    __shared__ short8 Wlds[16 * 8 * 64];       // [wave][ks][lane] = 128 KB (tile 3)

    const int blk = blockIdx.x;      // 0..63
    const int dir = blk >> 5;
    const int grp = blk & 31;
    const int B0  = grp * 2;
    const unsigned short* __restrict__ X = dir ? XB : XF;
    const float* __restrict__ Whh = dir ? w_hh_b : w_hh_f;
    float* __restrict__ Hout      = dir ? hb : hf;

    const int tid  = threadIdx.x;    // 0..1023
    const int w    = tid >> 6;       // wave 0..15
    const int lane = tid & 63;
    const int q    = lane >> 4;
    const int lr   = lane & 15;
    const int g    = w >> 2;         // gate (i,f,g,o)
    const int qt   = w & 3;          // unit quarter: units [qt*64, qt*64+64)

    // ---- stage W_hh bf16 B-fragments: tiles 0-2 -> regs (96 VGPR),
    //      tile 3 -> LDS. tile ntl rows: g*256 + qt*64 + ntl*16 + lr
    short8 wreg[3][8];
    #pragma unroll
    for (int ntl = 0; ntl < 4; ++ntl) {
        const float* wrow = &Whh[(size_t)(g * 256 + qt * 64 + ntl * 16 + lr) * 256];
        #pragma unroll
        for (int ks = 0; ks < 8; ++ks) {
            floatx4 a = *(const floatx4*)&wrow[ks * 32 + q * 8];
            floatx4 b = *(const floatx4*)&wrow[ks * 32 + q * 8 + 4];
            union { uint4 u4; short8 s; } cv;
            cv.u4 = make_uint4(pk_bf16(a.x, a.y), pk_bf16(a.z, a.w),
                               pk_bf16(b.x, b.y), pk_bf16(b.z, b.w));
            if (ntl < 3) wreg[ntl][ks] = cv.s;
            else         Wlds[(w * 8 + ks) * 64 + lane] = cv.s;
        }
    }

    // ---- chain state: threads tid<512 own (batch b_p, unit u_p)
    const int b_p = tid >> 8;        // 0..1 (valid for tid<512)
    const int u_p = tid & 255;
    const int sgi = (dir * 64 + B0 + b_p) * 256 + u_p;
    float cst = 0.f;
    float hlast = 0.f;
    if (t0 == 0) {
        for (int i = tid; i < 528; i += 1024) ((unsigned short*)Ah)[i] = 0;
    } else if (tid < 512) {
        cst = state_c[sgi];
        hlast = state_h[sgi];
        Ah[b_p][u_p] = bf16r(hlast);
    }

    for (int t = t0; t < t1; ++t) {
        // X for this step (bf16; independent of h, issued before the barrier)
        float xg[4];
        if (tid < 512) {
            const unsigned short* Xc = &X[((size_t)(t - t0) * 64 + B0 + b_p) * 1024 + u_p];
            #pragma unroll
            for (int gg = 0; gg < 4; ++gg)
                xg[gg] = bf16d(Xc[gg * 256]);
        }
        __syncthreads();   // Ah (and Wlds on iter 0) visible to all waves

        // phase A: ks-outer, 4 accumulators (tiles), 1 live A-fragment
        floatx4 c0 = {0,0,0,0}, c1 = {0,0,0,0}, c2 = {0,0,0,0}, c3 = {0,0,0,0};
        #pragma unroll
        for (int ks = 0; ks < 8; ++ks) {
            short8 a = *(const short8*)&Ah[lr & 1][ks * 32 + q * 8];
            short8 w3 = Wlds[(w * 8 + ks) * 64 + lane];
            c0 = __builtin_amdgcn_mfma_f32_16x16x32_bf16(a, wreg[0][ks], c0, 0, 0, 0);
            c1 = __builtin_amdgcn_mfma_f32_16x16x32_bf16(a, wreg[1][ks], c1, 0, 0, 0);
            c2 = __builtin_amdgcn_mfma_f32_16x16x32_bf16(a, wreg[2][ks], c2, 0, 0, 0);
            c3 = __builtin_amdgcn_mfma_f32_16x16x32_bf16(a, w3, c3, 0, 0, 0);
        }
        if (q == 0) {   // D rows 0..1 = batches 0..1
            int ub = qt * 64 + lr;
            scr[g][0][ub]      = c0[0];  scr[g][1][ub]      = c0[1];
            scr[g][0][ub + 16] = c1[0];  scr[g][1][ub + 16] = c1[1];
            scr[g][0][ub + 32] = c2[0];  scr[g][1][ub + 32] = c2[1];
            scr[g][0][ub + 48] = c3[0];  scr[g][1][ub + 48] = c3[1];
        }
        __syncthreads();   // scr ready; all Ah reads done

        // phase B: one (batch, unit) pair per thread (tid < 512)
        if (tid < 512) {
            float gi = scr[0][b_p][u_p] + xg[0];
            float gf = scr[1][b_p][u_p] + xg[1];
            float gg = scr[2][b_p][u_p] + xg[2];
            float go = scr[3][b_p][u_p] + xg[3];
            float ig = 1.f / (1.f + expf(-gi));
            float fg = 1.f / (1.f + expf(-gf));
            float gv = tanhf(gg);
            float og = 1.f / (1.f + expf(-go));
            cst = fg * cst + ig * gv;
            float h = og * tanhf(cst);
            hlast = h;
            int tt = dir ? (511 - t) : t;
            Hout[((size_t)tt * 64 + B0 + b_p) * 256 + u_p] = h;
            Ah[b_p][u_p] = bf16r(h);
        }
    }

    if (tid < 512) {
        state_c[sgi] = cst;
        state_h[sgi] = hlast;
    }
}

// ---------------------------------------------------------------------------
// Kernel 3: LayerNorm + classifier + argmax. One wave per (b,t).
// ---------------------------------------------------------------------------
__global__ __launch_bounds__(256) void ln_cls_kernel(
    const float* __restrict__ hf, const float* __restrict__ hb,
    const float* __restrict__ gamma, const float* __restrict__ beta,
    const float* __restrict__ cls_w, const float* __restrict__ cls_b,
    float* __restrict__ logits, float* __restrict__ dout)
{
    const int lane = threadIdx.x & 63;
    const int wid  = threadIdx.x >> 6;
    const int pos  = blockIdx.x * 4 + wid;   // 0..32767
    const int b = pos >> 9;
    const int t = pos & 511;

    float4 v0 = *(const float4*)&hf[((size_t)t * 64 + b) * 256 + lane * 4];
    float4 v1 = *(const float4*)&hb[((size_t)t * 64 + b) * 256 + lane * 4];
    float x[8] = {v0.x, v0.y, v0.z, v0.w, v1.x, v1.y, v1.z, v1.w};

    float s = 0.f;
    #pragma unroll
    for (int i = 0; i < 8; ++i) s += x[i];
    #pragma unroll
    for (int off = 32; off > 0; off >>= 1) s += __shfl_xor(s, off, 64);
    float mu = s * (1.f / 512.f);

    float d[8];
    float sq = 0.f;
    #pragma unroll
    for (int i = 0; i < 8; ++i) { d[i] = x[i] - mu; sq += d[i] * d[i]; }
    #pragma unroll
    for (int off = 32; off > 0; off >>= 1) sq += __shfl_xor(sq, off, 64);
    float rs = 1.f / sqrtf(sq * (1.f / 512.f) + 1e-5f);

    float4 g0  = *(const float4*)&gamma[lane * 4];
    float4 g1  = *(const float4*)&gamma[256 + lane * 4];
    float4 be0 = *(const float4*)&beta[lane * 4];
    float4 be1 = *(const float4*)&beta[256 + lane * 4];
    float y[8];
    y[0] = d[0] * rs * g0.x + be0.x; y[1] = d[1] * rs * g0.y + be0.y;
    y[2] = d[2] * rs * g0.z + be0.z; y[3] = d[3] * rs * g0.w + be0.w;
    y[4] = d[4] * rs * g1.x + be1.x; y[5] = d[5] * rs * g1.y + be1.y;
    y[6] = d[6] * rs * g1.z + be1.z; y[7] = d[7] * rs * g1.w + be1.w;

    float lgt[9];
    #pragma unroll
    for (int c = 0; c < 9; ++c) {
        float4 w0 = *(const float4*)&cls_w[c * 512 + lane * 4];
        float4 w1 = *(const float4*)&cls_w[c * 512 + 256 + lane * 4];
        float p = y[0] * w0.x + y[1] * w0.y + y[2] * w0.z + y[3] * w0.w
                + y[4] * w1.x + y[5] * w1.y + y[6] * w1.z + y[7] * w1.w;
        #pragma unroll
        for (int off = 32; off > 0; off >>= 1) p += __shfl_xor(p, off, 64);
        lgt[c] = p + cls_b[c];
    }
    if (lane == 0) {
        int bestc = 0;
        float bestv = lgt[0];
        #pragma unroll
        for (int c = 1; c < 9; ++c)
            if (lgt[c] > bestv) { bestv = lgt[c]; bestc = c; }  // strict >: first max
        dout[1 + pos] = (float)bestc;
        #pragma unroll
        for (int c = 0; c < 9; ++c) logits[(size_t)pos * 9 + c] = lgt[c];
    }
}

// ---------------------------------------------------------------------------
// Kernel 4: CRF numerator + forward algorithm (logZ). One wave per batch row.
// ---------------------------------------------------------------------------
__global__ __launch_bounds__(64) void crf_kernel(
    const float* __restrict__ logits, const int* __restrict__ label_ids,
    const float* __restrict__ crf_start, const float* __restrict__ crf_end,
    const float* __restrict__ crf_trans, float* __restrict__ llh)
{
    __shared__ float Ts[9][12];
    const int b = blockIdx.x;
    const int lane = threadIdx.x;
    if (lane < 81) Ts[lane / 9][lane % 9] = crf_trans[lane];
    __syncthreads();

    const float* __restrict__ em  = &logits[(size_t)b * 512 * 9];
    const int* __restrict__ tags  = &label_ids[b * 512];

    float part = 0.f;
    for (int t = lane; t < 512; t += 64) {
        int tg = tags[t];
        part += em[t * 9 + tg];
        if (t < 511) part += Ts[tg][tags[t + 1]];
    }
    #pragma unroll
    for (int off = 32; off > 0; off >>= 1) part += __shfl_xor(part, off, 64);
    float numer = part + crf_start[tags[0]] + crf_end[tags[511]];

    const int j = (lane < 9) ? lane : 0;
    float alpha = crf_start[j] + em[j];
    for (int t = 1; t < 512; ++t) {
        float av[9];
        float m = -1e30f;
        #pragma unroll
        for (int i = 0; i < 9; ++i) {
            float ai = __shfl(alpha, i, 64);
            av[i] = ai + Ts[i][j];
            m = fmaxf(m, av[i]);
        }
        float ssum = 0.f;
        #pragma unroll
        for (int i = 0; i < 9; ++i) ssum += expf(av[i] - m);
        alpha = m + logf(ssum) + em[t * 9 + j];
    }
    float v = (lane < 9) ? (alpha + crf_end[j]) : -1e30f;
    float mm = v;
    #pragma unroll
    for (int off = 32; off > 0; off >>= 1) mm = fmaxf(mm, __shfl_xor(mm, off, 64));
    float es = (lane < 9) ? expf(v - mm) : 0.f;
    #pragma unroll
    for (int off = 32; off > 0; off >>= 1) es += __shfl_xor(es, off, 64);
    if (lane == 0) llh[b] = numer - (mm + logf(es));
}

// ---------------------------------------------------------------------------
// Kernel 5: loss = -sum_b llh[b]
// ---------------------------------------------------------------------------
__global__ __launch_bounds__(64) void final_reduce(
    const float* __restrict__ llh, float* __restrict__ dout)
{
    float v = llh[threadIdx.x];
    #pragma unroll
    for (int off = 32; off > 0; off >>= 1) v += __shfl_xor(v, off, 64);
    if (threadIdx.x == 0) dout[0] = -v;
}

// ---------------------------------------------------------------------------
extern "C" void kernel_launch(void* const* d_in, const int* in_sizes, int n_in,
                              void* d_out, int out_size, void* d_ws, size_t ws_size,
                              hipStream_t stream)
{
    const int*   word_ids  = (const int*)d_in[0];
    const int*   label_ids = (const int*)d_in[1];
    const float* embed     = (const float*)d_in[2];
    const float* w_ih_f    = (const float*)d_in[3];
    const float* w_hh_f    = (const float*)d_in[4];
    const float* b_f       = (const float*)d_in[5];
    const float* w_ih_b    = (const float*)d_in[6];
    const float* w_hh_b    = (const float*)d_in[7];
    const float* b_b       = (const float*)d_in[8];
    const float* ln_gamma  = (const float*)d_in[9];
    const float* ln_beta   = (const float*)d_in[10];
    const float* cls_w     = (const float*)d_in[11];
    const float* cls_b     = (const float*)d_in[12];
    const float* crf_start = (const float*)d_in[13];
    const float* crf_end   = (const float*)d_in[14];
    const float* crf_trans = (const float*)d_in[15];

    char* w = (char*)d_ws;
    auto alloc = [&](size_t bytes) -> char* {
        char* p = w; w += (bytes + 255) & ~(size_t)255; return p;
    };
    float* hf      = (float*)alloc((size_t)8388608 * 4);   // [512][64][256]
    float* hb      = (float*)alloc((size_t)8388608 * 4);
    float* logits  = (float*)alloc((size_t)294912 * 4);    // [B*T][9]
    float* state_c = (float*)alloc((size_t)32768 * 4);     // [dir][64][256]
    float* state_h = (float*)alloc((size_t)32768 * 4);
    float* llh     = (float*)alloc((size_t)64 * 4);
    size_t fixed   = (size_t)(w - (char*)d_ws);

    // choose largest time-chunk L whose bf16 X buffers fit (L=512 expected)
    int L = 512;
    while (L > 32 && fixed + (size_t)L * 262144 > ws_size) L >>= 1;
    unsigned short* XF = (unsigned short*)alloc((size_t)L * 65536 * 2);  // [L][64][1024] bf16
    unsigned short* XB = (unsigned short*)alloc((size_t)L * 65536 * 2);
    int lgL = 31 - __builtin_clz((unsigned)L);

    for (int t0 = 0; t0 < 512; t0 += L) {
        proj_kernel<<<dim3(16, L, 2), 256, 0, stream>>>(
            word_ids, embed, w_ih_f, b_f, w_ih_b, b_b, XF, XB, t0, lgL);
        lstm_scan<<<64, 1024, 0, stream>>>(
            XF, XB, w_hh_f, w_hh_b, hf, hb, state_c, state_h, t0, t0 + L);
    }
    ln_cls_kernel<<<8192, 256, 0, stream>>>(
        hf, hb, ln_gamma, ln_beta, cls_w, cls_b, logits, (float*)d_out);
    crf_kernel<<<64, 64, 0, stream>>>(
        logits, label_ids, crf_start, crf_end, crf_trans, llh);
    final_reduce<<<1, 64, 0, stream>>>(llh, (float*)d_out);
}

// Round 18
// 1459.645 us; speedup vs baseline: 1.4310x; 1.4310x over previous
//
#include <hip/hip_runtime.h>
#include <cstdint>
#include <cmath>

typedef __attribute__((ext_vector_type(8))) short short8;   // 8 bf16 (4 VGPRs)
typedef __attribute__((ext_vector_type(4))) float floatx4;  // MFMA C/D

// round-to-nearest-even fp32->bf16, packed pair -> uint (lo = x, hi = y)
__device__ __forceinline__ unsigned pk_bf16(float x, float y) {
    unsigned ux = __float_as_uint(x); ux = ux + 0x7fffu + ((ux >> 16) & 1u);
    unsigned uy = __float_as_uint(y); uy = uy + 0x7fffu + ((uy >> 16) & 1u);
    return (ux >> 16) | (uy & 0xffff0000u);
}
__device__ __forceinline__ unsigned short bf16r(float x) {
    unsigned ux = __float_as_uint(x);
    return (unsigned short)((ux + 0x7fffu + ((ux >> 16) & 1u)) >> 16);
}
__device__ __forceinline__ float bf16d(unsigned short v) {
    return __uint_as_float((unsigned)v << 16);
}

// ---------------------------------------------------------------------------
// Kernel 1: fused embedding gather + input projections via bf16 MFMA.
// RESTRUCTURED (r17): one block per (n-tile, dir) stages the A (embedding)
// tile ONCE and loops over all 16 j-tiles, streaming W from L2 (W = 2 MB
// total, L2-resident, shared by all 512 n-blocks per dir). The old grid
// re-gathered A per j-tile: ~1 GB redundant reads. MFMA order per output
// is unchanged -> bitwise-identical X. LDS 66 KB -> 2 blocks/CU.
// ---------------------------------------------------------------------------
__global__ __launch_bounds__(256) void proj_kernel(
    const int* __restrict__ word_ids, const float* __restrict__ embed,
    const float* __restrict__ w_ih_f, const float* __restrict__ b_f,
    const float* __restrict__ w_ih_b, const float* __restrict__ b_b,
    unsigned short* __restrict__ XF, unsigned short* __restrict__ XB,
    int t0, int lgL)
{
    __shared__ unsigned short As[64][264];   // 64 x 256 bf16, +8 pad
    __shared__ unsigned short Bs[64][264];
    __shared__ int idx[64];

    const int tid = threadIdx.x;
    const int nt  = blockIdx.x;   // 0..L-1 (n tile; n = b*L + tl)
    const int dir = blockIdx.y;   // 0..1
    const int Lm1 = (1 << lgL) - 1;
    const float* __restrict__ W    = dir ? w_ih_b : w_ih_f;
    const float* __restrict__ bias = dir ? b_b : b_f;
    unsigned short* __restrict__ Xout = dir ? XB : XF;

    if (tid < 64) {
        int n  = nt * 64 + tid;
        int b  = n >> lgL;
        int tl = n & Lm1;
        int tg = dir ? (511 - (t0 + tl)) : (t0 + tl);
        idx[tid] = word_ids[b * 512 + tg];
    }
    __syncthreads();

    // stage A (embedding rows) once: 64 rows x 256 cols, bf16
    #pragma unroll
    for (int i = 0; i < 16; ++i) {
        int flat = i * 256 + tid;        // 0..4095 float4 units
        int r  = flat >> 6;              // row 0..63
        int kq = flat & 63;              // k = kq*4
        floatx4 a = *(const floatx4*)&embed[(size_t)idx[r] * 256 + kq * 4];
        *(uint2*)&As[r][kq * 4] = make_uint2(pk_bf16(a.x, a.y), pk_bf16(a.z, a.w));
    }
    __syncthreads();

    const int w    = tid >> 6;     // wave 0..3: n-rows [w*16, w*16+16)
    const int lane = tid & 63;
    const int q    = lane >> 4;    // k-quad
    const int lr   = lane & 15;

    // A-fragments in registers, reused across all 16 j-tiles
    short8 af[8];
    #pragma unroll
    for (int ks = 0; ks < 8; ++ks)
        af[ks] = *(const short8*)&As[w * 16 + lr][ks * 32 + q * 8];

    // n -> (b, tl) mapping for this thread's output rows (fixed across jt)
    int bb[4], tt4[4];
    #pragma unroll
    for (int reg = 0; reg < 4; ++reg) {
        int n  = nt * 64 + w * 16 + q * 4 + reg;
        bb[reg]  = n >> lgL;
        tt4[reg] = n & Lm1;
    }

    for (int jt = 0; jt < 16; ++jt) {
        __syncthreads();   // previous jt's Bs reads complete
        #pragma unroll
        for (int i = 0; i < 16; ++i) {
            int flat = i * 256 + tid;
            int r  = flat >> 6;
            int kq = flat & 63;
            floatx4 wv = *(const floatx4*)&W[(size_t)(jt * 64 + r) * 256 + kq * 4];
            *(uint2*)&Bs[r][kq * 4] = make_uint2(pk_bf16(wv.x, wv.y), pk_bf16(wv.z, wv.w));
        }
        __syncthreads();   // Bs staged

        #pragma unroll
        for (int jt4 = 0; jt4 < 4; ++jt4) {
            floatx4 c = {0.f, 0.f, 0.f, 0.f};
            #pragma unroll
            for (int ks = 0; ks < 8; ++ks) {
                short8 bf = *(const short8*)&Bs[jt4 * 16 + lr][ks * 32 + q * 8];
                c = __builtin_amdgcn_mfma_f32_16x16x32_bf16(af[ks], bf, c, 0, 0, 0);
            }
            int j = jt * 64 + jt4 * 16 + lr;
            float bj = bias[j];
            #pragma unroll
            for (int reg = 0; reg < 4; ++reg)
                Xout[((size_t)tt4[reg] * 64 + bb[reg]) * 1024 + j] = bf16r(c[reg] + bj);
        }
    }
}

// ---------------------------------------------------------------------------
// Kernel 2: BiLSTM scan — r16 verbatim (best passing: 1045 us/dispatch).
// Register-model finding (r9-r17): backend budgets 512/(waves-per-SIMD)
// regs/wave, split 50/50 arch/AGPR for MFMA kernels; arch cap is 128 at
// 8 waves (r11/r16), 64 at 16 waves (r17 regression). Spills at 8 waves go
// mostly to idle AGPRs (cheap) — the 2.04 us/step is the LDS-pipe +
// dependency floor of this structure, not a spill stream.
// ---------------------------------------------------------------------------
__global__ __launch_bounds__(512, 1)
__attribute__((amdgpu_num_vgpr(256)))
void lstm_scan(
    const unsigned short* __restrict__ XF, const unsigned short* __restrict__ XB,
    const float* __restrict__ w_hh_f, const float* __restrict__ w_hh_b,
    float* __restrict__ hf, float* __restrict__ hb,
    float* __restrict__ state_c, float* __restrict__ state_h, int t0, int t1)
{
    __shared__ unsigned short Ah[2][264];      // h(t-1) bf16: [batch][k=256(+8)]
    __shared__ float scr[4][2][256];           // gate preacts: [gate][batch][unit]
    __shared__ short8 Wlds[8 * 2 * 8 * 64];    // [wave][lds-tile][ks][lane] = 128 KB

    const int blk = blockIdx.x;      // 0..63
    const int dir = blk >> 5;
    const int grp = blk & 31;
    const int B0  = grp * 2;
    const unsigned short* __restrict__ X = dir ? XB : XF;
    const float* __restrict__ Whh = dir ? w_hh_b : w_hh_f;
    float* __restrict__ Hout      = dir ? hb : hf;

    const int tid  = threadIdx.x;    // 0..511
    const int w    = tid >> 6;       // wave 0..7
    const int lane = tid & 63;
    const int q    = lane >> 4;
    const int lr   = lane & 15;
    const int g    = w >> 1;         // gate (i,f,g,o)
    const int uh   = w & 1;          // unit half

    // ---- stage W_hh as bf16 B-fragments: tiles 0-5 -> regs, 6-7 -> LDS
    short8 wreg[6][8];
    #pragma unroll
    for (int ntl = 0; ntl < 8; ++ntl) {
        const float* wrow = &Whh[(size_t)(g * 256 + uh * 128 + ntl * 16 + lr) * 256];
        #pragma unroll
        for (int ks = 0; ks < 8; ++ks) {
            floatx4 a = *(const floatx4*)&wrow[ks * 32 + q * 8];
            floatx4 b = *(const floatx4*)&wrow[ks * 32 + q * 8 + 4];
            union { uint4 u4; short8 s; } cv;
            cv.u4 = make_uint4(pk_bf16(a.x, a.y), pk_bf16(a.z, a.w),
                               pk_bf16(b.x, b.y), pk_bf16(b.z, b.w));
            if (ntl < 6) wreg[ntl][ks] = cv.s;
            else         Wlds[((w * 2 + (ntl - 6)) * 8 + ks) * 64 + lane] = cv.s;
        }
    }

    // ---- chain state: thread owns (batch b_p, unit u_p)
    const int b_p = tid >> 8;        // 0..1
    const int u_p = tid & 255;
    const int sgi = (dir * 64 + B0 + b_p) * 256 + u_p;
    float cst = 0.f;
    float hlast = 0.f;
    if (t0 == 0) {
        Ah[b_p][u_p] = 0;
    } else {
        cst = state_c[sgi];
        hlast = state_h[sgi];
        Ah[b_p][u_p] = bf16r(hlast);
    }

    for (int t = t0; t < t1; ++t) {
        // X for this step (bf16; independent of h, issued before the barrier)
        float xg[4];
        {
            const unsigned short* Xc = &X[((size_t)(t - t0) * 64 + B0 + b_p) * 1024 + u_p];
            #pragma unroll
            for (int gg = 0; gg < 4; ++gg)
                xg[gg] = bf16d(Xc[gg * 256]);
        }
        __syncthreads();   // Ah (and Wlds on iter 0) visible to all waves

        // phase A: gates[m=batch][n] = h[2x256] @ Whh^T (wave = gate/half)
        short8 af[8];
        #pragma unroll
        for (int ks = 0; ks < 8; ++ks)
            af[ks] = *(const short8*)&Ah[lr & 1][ks * 32 + q * 8];
        #pragma unroll
        for (int ntl = 0; ntl < 8; ++ntl) {
            floatx4 c = {0.f, 0.f, 0.f, 0.f};
            #pragma unroll
            for (int ks = 0; ks < 8; ++ks) {
                if (ntl < 6)
                    c = __builtin_amdgcn_mfma_f32_16x16x32_bf16(af[ks], wreg[ntl][ks], c, 0, 0, 0);
                else
                    c = __builtin_amdgcn_mfma_f32_16x16x32_bf16(
                            af[ks], Wlds[((w * 2 + (ntl - 6)) * 8 + ks) * 64 + lane], c, 0, 0, 0);
            }
            if (q == 0) {   // D rows 0..1 = real batches
                scr[g][0][uh * 128 + ntl * 16 + lr] = c[0];
                scr[g][1][uh * 128 + ntl * 16 + lr] = c[1];
            }
        }
        __syncthreads();   // scr ready; all Ah reads done

        // phase B: one (batch, unit) pair per thread
        {
            float gi = scr[0][b_p][u_p] + xg[0];
            float gf = scr[1][b_p][u_p] + xg[1];
            float gg = scr[2][b_p][u_p] + xg[2];
            float go = scr[3][b_p][u_p] + xg[3];
            float ig = 1.f / (1.f + expf(-gi));
            float fg = 1.f / (1.f + expf(-gf));
            float gv = tanhf(gg);
            float og = 1.f / (1.f + expf(-go));
            cst = fg * cst + ig * gv;
            float h = og * tanhf(cst);
            hlast = h;
            int tt = dir ? (511 - t) : t;
            Hout[((size_t)tt * 64 + B0 + b_p) * 256 + u_p] = h;
            Ah[b_p][u_p] = bf16r(h);
        }
    }

    state_c[sgi] = cst;
    state_h[sgi] = hlast;
}

// ---------------------------------------------------------------------------
// Kernel 3: LayerNorm + classifier + argmax. One wave per (b,t).
// ---------------------------------------------------------------------------
__global__ __launch_bounds__(256) void ln_cls_kernel(
    const float* __restrict__ hf, const float* __restrict__ hb,
    const float* __restrict__ gamma, const float* __restrict__ beta,
    const float* __restrict__ cls_w, const float* __restrict__ cls_b,
    float* __restrict__ logits, float* __restrict__ dout)
{
    const int lane = threadIdx.x & 63;
    const int wid  = threadIdx.x >> 6;
    const int pos  = blockIdx.x * 4 + wid;   // 0..32767
    const int b = pos >> 9;
    const int t = pos & 511;

    float4 v0 = *(const float4*)&hf[((size_t)t * 64 + b) * 256 + lane * 4];
    float4 v1 = *(const float4*)&hb[((size_t)t * 64 + b) * 256 + lane * 4];
    float x[8] = {v0.x, v0.y, v0.z, v0.w, v1.x, v1.y, v1.z, v1.w};

    float s = 0.f;
    #pragma unroll
    for (int i = 0; i < 8; ++i) s += x[i];
    #pragma unroll
    for (int off = 32; off > 0; off >>= 1) s += __shfl_xor(s, off, 64);
    float mu = s * (1.f / 512.f);

    float d[8];
    float sq = 0.f;
    #pragma unroll
    for (int i = 0; i < 8; ++i) { d[i] = x[i] - mu; sq += d[i] * d[i]; }
    #pragma unroll
    for (int off = 32; off > 0; off >>= 1) sq += __shfl_xor(sq, off, 64);
    float rs = 1.f / sqrtf(sq * (1.f / 512.f) + 1e-5f);

    float4 g0  = *(const float4*)&gamma[lane * 4];
    float4 g1  = *(const float4*)&gamma[256 + lane * 4];
    float4 be0 = *(const float4*)&beta[lane * 4];
    float4 be1 = *(const float4*)&beta[256 + lane * 4];
    float y[8];
    y[0] = d[0] * rs * g0.x + be0.x; y[1] = d[1] * rs * g0.y + be0.y;
    y[2] = d[2] * rs * g0.z + be0.z; y[3] = d[3] * rs * g0.w + be0.w;
    y[4] = d[4] * rs * g1.x + be1.x; y[5] = d[5] * rs * g1.y + be1.y;
    y[6] = d[6] * rs * g1.z + be1.z; y[7] = d[7] * rs * g1.w + be1.w;

    float lgt[9];
    #pragma unroll
    for (int c = 0; c < 9; ++c) {
        float4 w0 = *(const float4*)&cls_w[c * 512 + lane * 4];
        float4 w1 = *(const float4*)&cls_w[c * 512 + 256 + lane * 4];
        float p = y[0] * w0.x + y[1] * w0.y + y[2] * w0.z + y[3] * w0.w
                + y[4] * w1.x + y[5] * w1.y + y[6] * w1.z + y[7] * w1.w;
        #pragma unroll
        for (int off = 32; off > 0; off >>= 1) p += __shfl_xor(p, off, 64);
        lgt[c] = p + cls_b[c];
    }
    if (lane == 0) {
        int bestc = 0;
        float bestv = lgt[0];
        #pragma unroll
        for (int c = 1; c < 9; ++c)
            if (lgt[c] > bestv) { bestv = lgt[c]; bestc = c; }  // strict >: first max
        dout[1 + pos] = (float)bestc;
        #pragma unroll
        for (int c = 0; c < 9; ++c) logits[(size_t)pos * 9 + c] = lgt[c];
    }
}

// ---------------------------------------------------------------------------
// Kernel 4: CRF numerator + forward algorithm (logZ). One wave per batch row.
// ---------------------------------------------------------------------------
__global__ __launch_bounds__(64) void crf_kernel(
    const float* __restrict__ logits, const int* __restrict__ label_ids,
    const float* __restrict__ crf_start, const float* __restrict__ crf_end,
    const float* __restrict__ crf_trans, float* __restrict__ llh)
{
    __shared__ float Ts[9][12];
    const int b = blockIdx.x;
    const int lane = threadIdx.x;
    if (lane < 81) Ts[lane / 9][lane % 9] = crf_trans[lane];
    __syncthreads();

    const float* __restrict__ em  = &logits[(size_t)b * 512 * 9];
    const int* __restrict__ tags  = &label_ids[b * 512];

    float part = 0.f;
    for (int t = lane; t < 512; t += 64) {
        int tg = tags[t];
        part += em[t * 9 + tg];
        if (t < 511) part += Ts[tg][tags[t + 1]];
    }
    #pragma unroll
    for (int off = 32; off > 0; off >>= 1) part += __shfl_xor(part, off, 64);
    float numer = part + crf_start[tags[0]] + crf_end[tags[511]];

    const int j = (lane < 9) ? lane : 0;
    float alpha = crf_start[j] + em[j];
    for (int t = 1; t < 512; ++t) {
        float av[9];
        float m = -1e30f;
        #pragma unroll
        for (int i = 0; i < 9; ++i) {
            float ai = __shfl(alpha, i, 64);
            av[i] = ai + Ts[i][j];
            m = fmaxf(m, av[i]);
        }
        float ssum = 0.f;
        #pragma unroll
        for (int i = 0; i < 9; ++i) ssum += expf(av[i] - m);
        alpha = m + logf(ssum) + em[t * 9 + j];
    }
    float v = (lane < 9) ? (alpha + crf_end[j]) : -1e30f;
    float mm = v;
    #pragma unroll
    for (int off = 32; off > 0; off >>= 1) mm = fmaxf(mm, __shfl_xor(mm, off, 64));
    float es = (lane < 9) ? expf(v - mm) : 0.f;
    #pragma unroll
    for (int off = 32; off > 0; off >>= 1) es += __shfl_xor(es, off, 64);
    if (lane == 0) llh[b] = numer - (mm + logf(es));
}

// ---------------------------------------------------------------------------
// Kernel 5: loss = -sum_b llh[b]
// ---------------------------------------------------------------------------
__global__ __launch_bounds__(64) void final_reduce(
    const float* __restrict__ llh, float* __restrict__ dout)
{
    float v = llh[threadIdx.x];
    #pragma unroll
    for (int off = 32; off > 0; off >>= 1) v += __shfl_xor(v, off, 64);
    if (threadIdx.x == 0) dout[0] = -v;
}

// ---------------------------------------------------------------------------
extern "C" void kernel_launch(void* const* d_in, const int* in_sizes, int n_in,
                              void* d_out, int out_size, void* d_ws, size_t ws_size,
                              hipStream_t stream)
{
    const int*   word_ids  = (const int*)d_in[0];
    const int*   label_ids = (const int*)d_in[1];
    const float* embed     = (const float*)d_in[2];
    const float* w_ih_f    = (const float*)d_in[3];
    const float* w_hh_f    = (const float*)d_in[4];
    const float* b_f       = (const float*)d_in[5];
    const float* w_ih_b    = (const float*)d_in[6];
    const float* w_hh_b    = (const float*)d_in[7];
    const float* b_b       = (const float*)d_in[8];
    const float* ln_gamma  = (const float*)d_in[9];
    const float* ln_beta   = (const float*)d_in[10];
    const float* cls_w     = (const float*)d_in[11];
    const float* cls_b     = (const float*)d_in[12];
    const float* crf_start = (const float*)d_in[13];
    const float* crf_end   = (const float*)d_in[14];
    const float* crf_trans = (const float*)d_in[15];

    char* w = (char*)d_ws;
    auto alloc = [&](size_t bytes) -> char* {
        char* p = w; w += (bytes + 255) & ~(size_t)255; return p;
    };
    float* hf      = (float*)alloc((size_t)8388608 * 4);   // [512][64][256]
    float* hb      = (float*)alloc((size_t)8388608 * 4);
    float* logits  = (float*)alloc((size_t)294912 * 4);    // [B*T][9]
    float* state_c = (float*)alloc((size_t)32768 * 4);     // [dir][64][256]
    float* state_h = (float*)alloc((size_t)32768 * 4);
    float* llh     = (float*)alloc((size_t)64 * 4);
    size_t fixed   = (size_t)(w - (char*)d_ws);

    // choose largest time-chunk L whose bf16 X buffers fit (L=512 expected)
    int L = 512;
    while (L > 32 && fixed + (size_t)L * 262144 > ws_size) L >>= 1;
    unsigned short* XF = (unsigned short*)alloc((size_t)L * 65536 * 2);  // [L][64][1024] bf16
    unsigned short* XB = (unsigned short*)alloc((size_t)L * 65536 * 2);
    int lgL = 31 - __builtin_clz((unsigned)L);

    for (int t0 = 0; t0 < 512; t0 += L) {
        proj_kernel<<<dim3(L, 2), 256, 0, stream>>>(
            word_ids, embed, w_ih_f, b_f, w_ih_b, b_b, XF, XB, t0, lgL);
        lstm_scan<<<64, 512, 0, stream>>>(
            XF, XB, w_hh_f, w_hh_b, hf, hb, state_c, state_h, t0, t0 + L);
    }
    ln_cls_kernel<<<8192, 256, 0, stream>>>(
        hf, hb, ln_gamma, ln_beta, cls_w, cls_b, logits, (float*)d_out);
    crf_kernel<<<64, 64, 0, stream>>>(
        logits, label_ids, crf_start, crf_end, crf_trans, llh);
    final_reduce<<<1, 64, 0, stream>>>(llh, (float*)d_out);
}